// Round 5
// baseline (168.762 us; speedup 1.0000x reference)
//
#include <hip/hip_runtime.h>
#include <hip/hip_bf16.h>
#include <math.h>

typedef unsigned short u16;
typedef short bf16x8 __attribute__((ext_vector_type(8)));
typedef float f32x4 __attribute__((ext_vector_type(4)));

__device__ __forceinline__ u16 f2b(float f) {
    __hip_bfloat16 h = __float2bfloat16(f);
    return *reinterpret_cast<u16*>(&h);
}
__device__ __forceinline__ float b2f(u16 v) {
    __hip_bfloat16 h;
    *reinterpret_cast<u16*>(&h) = v;
    return __bfloat162float(h);
}

__device__ __forceinline__ void gload_lds16(const void* g, void* l) {
    __builtin_amdgcn_global_load_lds(
        (const __attribute__((address_space(1))) void*)g,
        (__attribute__((address_space(3))) void*)l, 16, 0, 0);
}

// ---------------- epilogues ----------------

// Tile epilogue for transposed QKV GEMM: rowp = weight-col base (4 consecutive
// values in vals), colp = pos index. Q/K stores ushort4 coalesced; V stores
// transposed (VT[bh][d][t]) directly.
struct EpiQKV4 {
    u16 *Q, *Kt, *Vt;
    __device__ void operator()(int rowp, int colp, f32x4 vals) const {
        int b = colp >> 9, pos = colp & 511;
        int sec = rowp >> 10, cc = rowp & 1023;
        int head = cc >> 6, d0 = cc & 63;
        if (sec == 0) {
            if (pos < 256) return;
            ushort4 o;
            o.x = f2b(vals[0] * 0.125f); o.y = f2b(vals[1] * 0.125f);
            o.z = f2b(vals[2] * 0.125f); o.w = f2b(vals[3] * 0.125f);
            *(ushort4*)(Q + (long)((head * 8 + b) * 256 + (pos - 256)) * 64 + d0) = o;
        } else if (sec == 1) {
            ushort4 o;
            o.x = f2b(vals[0]); o.y = f2b(vals[1]);
            o.z = f2b(vals[2]); o.w = f2b(vals[3]);
            *(ushort4*)(Kt + (long)((b * 16 + head) * 512 + pos) * 64 + d0) = o;
        } else {
            // transposed store: VT[(b*16+head)*64 + d][pos]
            #pragma unroll
            for (int r = 0; r < 4; ++r)
                Vt[(long)((b * 16 + head) * 64 + d0 + r) * 512 + pos] = f2b(vals[r]);
        }
    }
};

struct EpiStoreBf {
    u16* C; long ldc; long strideZ;
    __device__ void operator()(int z, int row, int col, float val) const {
        C[(long)z * strideZ + (long)row * ldc + col] = f2b(val);
    }
};

// ---------------- 64x64-tile GEMM body (C = A @ B^T), LDS-staged ----------------
// Requires 14336 bytes of smem (2 x 64 x 56 x 2B).
// AF32: A is f32, converted during staging. ROWMAP: A row remap.

template <typename Epi, bool AF32, bool ROWMAP>
__device__ __forceinline__ void gemm_bt_body(char* smem, int bx, int by, int bz,
                                             const void* __restrict__ Av, int lda, long strideAz,
                                             const u16* __restrict__ B, int ldb, long strideBz,
                                             int K, Epi epi) {
    constexpr int LDT = 56;
    u16* As = (u16*)smem;
    u16* Bs = As + 64 * LDT;
    int n0 = bx * 64, m0 = by * 64, z = bz;
    const u16* Bb = B + (long)z * strideBz + (long)n0 * ldb;
    int tid = threadIdx.x;
    int wave = tid >> 6, lane = tid & 63;
    int wm = wave >> 1, wn = wave & 1;
    int lrow = lane & 15, lquad = lane >> 4;
    int srow = tid >> 2, scol = (tid & 3) * 8;
    f32x4 acc[2][2] = {};
    for (int k0 = 0; k0 < K; k0 += 32) {
        if constexpr (AF32) {
            long arow = m0 + srow;
            if constexpr (ROWMAP) arow = (arow < 256) ? 768 + arow : 0;
            const float* src = (const float*)Av + (long)z * strideAz + arow * lda + k0 + scol;
            float4 f0 = *(const float4*)src;
            float4 f1 = *(const float4*)(src + 4);
            bf16x8 vv;
            vv[0] = (short)f2b(f0.x); vv[1] = (short)f2b(f0.y);
            vv[2] = (short)f2b(f0.z); vv[3] = (short)f2b(f0.w);
            vv[4] = (short)f2b(f1.x); vv[5] = (short)f2b(f1.y);
            vv[6] = (short)f2b(f1.z); vv[7] = (short)f2b(f1.w);
            *(bf16x8*)(As + srow * LDT + scol) = vv;
        } else {
            const u16* Ab = (const u16*)Av + (long)z * strideAz + (long)m0 * lda;
            *(bf16x8*)(As + srow * LDT + scol) = *(const bf16x8*)(Ab + (long)srow * lda + k0 + scol);
        }
        *(bf16x8*)(Bs + srow * LDT + scol) = *(const bf16x8*)(Bb + (long)srow * ldb + k0 + scol);
        __syncthreads();
        bf16x8 af[2], bfr[2];
        #pragma unroll
        for (int mt = 0; mt < 2; ++mt)
            af[mt] = *(const bf16x8*)(As + (wm * 32 + mt * 16 + lrow) * LDT + lquad * 8);
        #pragma unroll
        for (int nt = 0; nt < 2; ++nt)
            bfr[nt] = *(const bf16x8*)(Bs + (wn * 32 + nt * 16 + lrow) * LDT + lquad * 8);
        #pragma unroll
        for (int mt = 0; mt < 2; ++mt)
            #pragma unroll
            for (int nt = 0; nt < 2; ++nt)
                acc[mt][nt] = __builtin_amdgcn_mfma_f32_16x16x32_bf16(af[mt], bfr[nt], acc[mt][nt], 0, 0, 0);
        __syncthreads();
    }
    #pragma unroll
    for (int mt = 0; mt < 2; ++mt)
        #pragma unroll
        for (int nt = 0; nt < 2; ++nt)
            #pragma unroll
            for (int r = 0; r < 4; ++r) {
                int row = m0 + wm * 32 + mt * 16 + lquad * 4 + r;
                int col = n0 + wn * 32 + nt * 16 + lrow;
                epi(z, row, col, acc[mt][nt][r]);
            }
}

// ---------------- prep: cast_cat + all three weight transposes + VT guard ----------------
// grid: [0,2048) cast_cat; [2048,5120) Wqkv; [5120,6144) Wkr; [6144,7168) Wout;
// 7168: zero the 1 KB guard after VT.
__global__ __launch_bounds__(256) void prep_kernel(const float* __restrict__ x,
                                                   const float* __restrict__ h,
                                                   u16* __restrict__ catBF,
                                                   const float* __restrict__ Wqkv, u16* __restrict__ WqkvT,
                                                   const float* __restrict__ Wkr,  u16* __restrict__ WkrT,
                                                   const float* __restrict__ Wout, u16* __restrict__ WoutT,
                                                   u16* __restrict__ vtGuard) {
    __shared__ float tile[32][33];
    int bid = blockIdx.x, tid = threadIdx.x;
    if (bid == 7168) {
        ((unsigned int*)vtGuard)[tid] = 0u;
        return;
    }
    if (bid < 2048) {
        int idx = (bid * 256 + tid) * 8;
        int c = idx & 1023, r = idx >> 10;
        int b = r >> 9, pos = r & 511;
        const float* src = (pos < 256) ? h + ((long)(b * 256 + pos) * 1024 + c)
                                       : x + ((long)(b * 256 + pos - 256) * 1024 + c);
        float4 f0 = *(const float4*)src;
        float4 f1 = *(const float4*)(src + 4);
        bf16x8 vv;
        vv[0] = (short)f2b(f0.x); vv[1] = (short)f2b(f0.y);
        vv[2] = (short)f2b(f0.z); vv[3] = (short)f2b(f0.w);
        vv[4] = (short)f2b(f1.x); vv[5] = (short)f2b(f1.y);
        vv[6] = (short)f2b(f1.z); vv[7] = (short)f2b(f1.w);
        *(bf16x8*)(catBF + idx) = vv;
        return;
    }
    const float* W; u16* WT; int nb, kb;
    if (bid < 5120) {
        int w = bid - 2048;  // 96 x 32 tiles
        W = Wqkv; WT = WqkvT;
        nb = (w % 96) * 32; kb = (w / 96) * 32;
        int tx = tid & 31, ty = tid >> 5;
        #pragma unroll
        for (int i = 0; i < 32; i += 8)
            tile[ty + i][tx] = W[(long)(kb + ty + i) * 3072 + nb + tx];
    } else {
        int w = bid - 5120;
        if (w < 1024) { W = Wkr; WT = WkrT; }
        else          { W = Wout; WT = WoutT; w -= 1024; }
        nb = (w & 31) * 32; kb = (w >> 5) * 32;
        int tx = tid & 31, ty = tid >> 5;
        #pragma unroll
        for (int i = 0; i < 32; i += 8)
            tile[ty + i][tx] = W[(long)(kb + ty + i) * 1024 + nb + tx];
    }
    __syncthreads();
    int row = tid >> 3;
    int c4 = (tid & 7) * 4;
    ushort4 o;
    o.x = f2b(tile[c4 + 0][row]);
    o.y = f2b(tile[c4 + 1][row]);
    o.z = f2b(tile[c4 + 2][row]);
    o.w = f2b(tile[c4 + 3][row]);
    *(ushort4*)(WT + (long)(nb + row) * 1024 + kb + c4) = o;
}

// ---------------- QKV GEMM (64x128 tiles, BK=32 dbuf, counted vmcnt) + RWg ----------------
// Round-4 re-tile: 128x128 -> 64x128 to fix grid starvation (640 -> 1280 live
// blocks, 2.8 -> 5 blocks/CU). LDS 24 KB/block, launch_bounds(256,5).
// Supertile geometry preserved (two 64-row m-halves x 8 n-panels per
// supertile) so the per-XCD L2 working set is identical to round-3.
// bid < 80: RWg (first, so the 80 K=1024 stragglers start early).
// bid >= 80: QKV tiles (1024 K/V + 256 live-Q).
__global__ __launch_bounds__(256, 5) void qkv_rwg_kernel(const u16* __restrict__ A, const u16* __restrict__ B,
                                                         EpiQKV4 eq,
                                                         const float* __restrict__ R, const u16* __restrict__ WkrT,
                                                         u16* __restrict__ RWg) {
    __shared__ alignas(16) char smem[24576];
    int bid0 = blockIdx.x;
    if (bid0 < 80) {
        gemm_bt_body<EpiStoreBf, true, true>(smem, bid0 & 15, bid0 >> 4, 0,
            (const void*)R, 1024, 0L, WkrT, 1024, 0L, 1024, EpiStoreBf{RWg, 1024, 0});
        return;
    }
    int q = bid0 - 80;                     // [0,1280)
    int xcd = q & 7, s = q >> 3;           // s in [0,160): XCD-local index
    int G = xcd * 10 + (s >> 4);           // supertile id [0,80)
    int w = s & 15;                        // block within supertile
    int m0, n0;
    if (G < 64) {                          // K/V: 16 m-128-panels x 4 n-chunks
        int nchunk = G >> 4, mrow = G & 15;
        m0 = 1024 + mrow * 128 + (w & 1) * 64;
        n0 = (nchunk * 8 + (w >> 1)) * 128;
    } else {                               // Q (live cols): 8 m-128-panels x 2 n-chunks
        int G2 = G - 64;
        int nchunk = G2 >> 3, mrow = G2 & 7;
        m0 = mrow * 128 + (w & 1) * 64;
        int c = nchunk * 8 + (w >> 1);     // live col index [0,16)
        n0 = (c >> 1) * 512 + 256 + (c & 1) * 128;
    }
    int tid = threadIdx.x, wave = tid >> 6, lane = tid & 63;
    int lrow = lane & 15, lquad = lane >> 4;
    const u16* Ab = A + (long)m0 * 1024;
    const u16* Bb = B + (long)n0 * 1024;
    f32x4 acc[4][2] = {};

    // buffer b: As [64][32] at b*6144 (u16), Bs [128][32] at +2048.
    auto stage = [&](int buf, int k0) {
        u16* Asb = (u16*)smem + buf * 6144;
        u16* Bsb = Asb + 2048;
        int row = tid >> 2, col = k0 + (tid & 3) * 8;
        gload_lds16(Ab + (long)row * 1024 + col, Asb + tid * 8);
        #pragma unroll
        for (int i = 0; i < 2; ++i)
            gload_lds16(Bb + (long)(i * 64 + row) * 1024 + col, Bsb + i * 2048 + tid * 8);
    };
    auto compute = [&](int buf) {
        u16* Asb = (u16*)smem + buf * 6144;
        u16* Bsb = Asb + 2048;
        bf16x8 af[4], bfr[2];
        #pragma unroll
        for (int mt = 0; mt < 4; ++mt)
            af[mt] = *(const bf16x8*)(Asb + (mt * 16 + lrow) * 32 + lquad * 8);
        #pragma unroll
        for (int nt = 0; nt < 2; ++nt)
            bfr[nt] = *(const bf16x8*)(Bsb + (wave * 32 + nt * 16 + lrow) * 32 + lquad * 8);
        #pragma unroll
        for (int mt = 0; mt < 4; ++mt)
            #pragma unroll
            for (int nt = 0; nt < 2; ++nt)
                acc[mt][nt] = __builtin_amdgcn_mfma_f32_16x16x32_bf16(af[mt], bfr[nt], acc[mt][nt], 0, 0, 0);
    };

    stage(0, 0);
    stage(1, 32);
    for (int t = 0; t < 31; ++t) {
        // wait for tile t's 3 loads; tile t+1's 3 remain in flight
        asm volatile("s_waitcnt vmcnt(3)" ::: "memory");
        __builtin_amdgcn_sched_barrier(0);
        __builtin_amdgcn_s_barrier();
        __builtin_amdgcn_sched_barrier(0);
        compute(t & 1);
        __builtin_amdgcn_sched_barrier(0);
        __builtin_amdgcn_s_barrier();          // all waves done reading buf before restage
        __builtin_amdgcn_sched_barrier(0);
        if (t < 30) stage(t & 1, (t + 2) * 32);
    }
    asm volatile("s_waitcnt vmcnt(0)" ::: "memory");
    __builtin_amdgcn_sched_barrier(0);
    __builtin_amdgcn_s_barrier();
    __builtin_amdgcn_sched_barrier(0);
    compute(1);

    #pragma unroll
    for (int mt = 0; mt < 4; ++mt)
        #pragma unroll
        for (int nt = 0; nt < 2; ++nt) {
            int rowp = m0 + mt * 16 + lquad * 4;
            int colp = n0 + wave * 32 + nt * 16 + lrow;
            eq(rowp, colp, acc[mt][nt]);
        }
}

// ---------------- out-proj: 64x64 tiles, BK=32 dbuf, counted vmcnt ----------------
// out[2048][1024] f32 = attnO @ WoutT^T. 512 blocks, 32 K-steps, 16 KB LDS.
__global__ __launch_bounds__(256, 4) void outproj_kernel(const u16* __restrict__ A,
                                                         const u16* __restrict__ B,
                                                         float* __restrict__ out) {
    __shared__ alignas(16) char smem[16384];
    int bid = blockIdx.x;
    int n0 = (bid & 15) * 64, m0 = (bid >> 4) * 64;
    int tid = threadIdx.x, wave = tid >> 6, lane = tid & 63;
    int wm = wave >> 1, wn = wave & 1;
    int lrow = lane & 15, lquad = lane >> 4;
    const u16* Ab = A + (long)m0 * 1024;
    const u16* Bb = B + (long)n0 * 1024;
    f32x4 acc[2][2] = {};

    // buffer b: As [64][32] at b*4096 (u16), Bs [64][32] at +2048.
    auto stage = [&](int buf, int k0) {
        u16* Asb = (u16*)smem + buf * 4096;
        u16* Bsb = Asb + 2048;
        int row = tid >> 2, col = k0 + (tid & 3) * 8;
        gload_lds16(Ab + (long)row * 1024 + col, Asb + tid * 8);
        gload_lds16(Bb + (long)row * 1024 + col, Bsb + tid * 8);
    };
    auto compute = [&](int buf) {
        u16* Asb = (u16*)smem + buf * 4096;
        u16* Bsb = Asb + 2048;
        bf16x8 af[2], bfr[2];
        #pragma unroll
        for (int mt = 0; mt < 2; ++mt)
            af[mt] = *(const bf16x8*)(Asb + (wm * 32 + mt * 16 + lrow) * 32 + lquad * 8);
        #pragma unroll
        for (int nt = 0; nt < 2; ++nt)
            bfr[nt] = *(const bf16x8*)(Bsb + (wn * 32 + nt * 16 + lrow) * 32 + lquad * 8);
        #pragma unroll
        for (int mt = 0; mt < 2; ++mt)
            #pragma unroll
            for (int nt = 0; nt < 2; ++nt)
                acc[mt][nt] = __builtin_amdgcn_mfma_f32_16x16x32_bf16(af[mt], bfr[nt], acc[mt][nt], 0, 0, 0);
    };

    stage(0, 0);
    stage(1, 32);
    for (int t = 0; t < 31; ++t) {
        asm volatile("s_waitcnt vmcnt(2)" ::: "memory");
        __builtin_amdgcn_sched_barrier(0);
        __builtin_amdgcn_s_barrier();
        __builtin_amdgcn_sched_barrier(0);
        compute(t & 1);
        __builtin_amdgcn_sched_barrier(0);
        __builtin_amdgcn_s_barrier();
        __builtin_amdgcn_sched_barrier(0);
        if (t < 30) stage(t & 1, (t + 2) * 32);
    }
    asm volatile("s_waitcnt vmcnt(0)" ::: "memory");
    __builtin_amdgcn_sched_barrier(0);
    __builtin_amdgcn_s_barrier();
    __builtin_amdgcn_sched_barrier(0);
    compute(1);

    #pragma unroll
    for (int mt = 0; mt < 2; ++mt)
        #pragma unroll
        for (int nt = 0; nt < 2; ++nt)
            #pragma unroll
            for (int r = 0; r < 4; ++r)
                out[(long)(m0 + wm * 32 + mt * 16 + lquad * 4 + r) * 1024
                    + n0 + wn * 32 + nt * 16 + lrow] = acc[mt][nt][r];
}

// ---------------- fused attention: 32 query rows per block, QR GEMM fused in ----------------
// Band structure: entry (i,j) visible iff 0 <= j-i <= 256; QR shift column is
// exactly d = j-i. Rows [i0,i0+32) see keys in [i0, i0+288]; we compute a
// 320-key window starting at w0=i0 (5 key-tiles per wave).
// The 32x320 QR tile (= 0.125(q+v) @ RWg[:, h*64:+64]^T, K=64) is computed
// in-kernel and written into the SQ LDS buffer. Out-of-range K reads at it=7
// land in VT (finite); OOB VT reads land in the zeroed guard.
// QR tile and P alias the same SQ buffer (lifetimes separated by the row-max
// __syncthreads) -> ~22 KB -> 4 blocks/CU.
__global__ __launch_bounds__(256, 4) void attn_kernel(const u16* __restrict__ Qs,
                                                      const u16* __restrict__ Kt,
                                                      const u16* __restrict__ VT,
                                                      const u16* __restrict__ RWg,
                                                      const float* __restrict__ uvec,
                                                      const float* __restrict__ vvec,
                                                      u16* __restrict__ attnOut) {
    constexpr int LDSW = 328;          // 320 + 8 pad; 656B row stride = 2-way banks (free)
    __shared__ alignas(16) u16 SQ[32 * LDSW];   // phase 1: QR tile; phase 2: P
    __shared__ float red[2][4][32];
    int id = blockIdx.x;
    int bh = id & 127, it = id >> 7;
    int b = bh >> 4, h = bh & 15;
    int i0 = it * 32;
    int w0 = i0;                       // key window [w0, w0+320)
    int tid = threadIdx.x, wave = tid >> 6, lane = tid & 63;
    int lrow = lane & 15, lquad = lane >> 4;

    // Q fragments: aq = 0.125q + 0.125u (QK), aqv = 0.125q + 0.125v (QR)
    bf16x8 aq[2][2], aqv[2][2];
    #pragma unroll
    for (int iu = 0; iu < 2; ++iu) {
        const u16* qbase = Qs + (long)((h * 8 + b) * 256 + i0 + iu * 16 + lrow) * 64;
        bf16x8 q0 = *(const bf16x8*)(qbase + lquad * 8);
        bf16x8 q1 = *(const bf16x8*)(qbase + 32 + lquad * 8);
        #pragma unroll
        for (int j = 0; j < 8; ++j) {
            float f0 = b2f((u16)q0[j]), f1 = b2f((u16)q1[j]);
            aq[iu][0][j]  = (short)f2b(f0 + 0.125f * uvec[lquad * 8 + j]);
            aq[iu][1][j]  = (short)f2b(f1 + 0.125f * uvec[32 + lquad * 8 + j]);
            aqv[iu][0][j] = (short)f2b(f0 + 0.125f * vvec[lquad * 8 + j]);
            aqv[iu][1][j] = (short)f2b(f1 + 0.125f * vvec[32 + lquad * 8 + j]);
        }
    }

    // fused QR tile -> SQ[rloc][sc], sc = wave*80 + t*16 + lrow
    const u16* rwbase = RWg + (long)(wave * 80) * 1024 + h * 64;
    #pragma unroll
    for (int t = 0; t < 5; ++t) {
        const u16* rp = rwbase + (long)(t * 16 + lrow) * 1024;
        bf16x8 br0 = *(const bf16x8*)(rp + lquad * 8);
        bf16x8 br1 = *(const bf16x8*)(rp + 32 + lquad * 8);
        int sc = wave * 80 + t * 16 + lrow;
        #pragma unroll
        for (int iu = 0; iu < 2; ++iu) {
            f32x4 qa = {0.f, 0.f, 0.f, 0.f};
            qa = __builtin_amdgcn_mfma_f32_16x16x32_bf16(aqv[iu][0], br0, qa, 0, 0, 0);
            qa = __builtin_amdgcn_mfma_f32_16x16x32_bf16(aqv[iu][1], br1, qa, 0, 0, 0);
            #pragma unroll
            for (int r = 0; r < 4; ++r)
                SQ[(iu * 16 + lquad * 4 + r) * LDSW + sc] = f2b(qa[r]);
        }
    }

    // QK^T over 5 key-tiles per wave (wave owns local keys [wave*80, wave*80+80))
    const u16* kbase = Kt + ((long)bh * 512 + w0 + wave * 80) * 64;
    bf16x8 bk0[5], bk1[5];
    #pragma unroll
    for (int t = 0; t < 5; ++t) {
        const u16* kp = kbase + (long)(t * 16 + lrow) * 64;
        bk0[t] = *(const bf16x8*)(kp + lquad * 8);
        bk1[t] = *(const bf16x8*)(kp + 32 + lquad * 8);
    }
    f32x4 acc[2][5];
    #pragma unroll
    for (int t = 0; t < 5; ++t)
        #pragma unroll
        for (int iu = 0; iu < 2; ++iu) {
            f32x4 a = {0.f, 0.f, 0.f, 0.f};
            a = __builtin_amdgcn_mfma_f32_16x16x32_bf16(aq[iu][0], bk0[t], a, 0, 0, 0);
            a = __builtin_amdgcn_mfma_f32_16x16x32_bf16(aq[iu][1], bk1[t], a, 0, 0, 0);
            acc[iu][t] = a;
        }
    __syncthreads();   // QR tile in LDS complete

    // mask + QR bias + row max.  d = j - i; visible iff 0 <= d <= 256.
    float m4[2][4];
    #pragma unroll
    for (int iu = 0; iu < 2; ++iu)
        #pragma unroll
        for (int r = 0; r < 4; ++r) m4[iu][r] = -1e30f;
    #pragma unroll
    for (int t = 0; t < 5; ++t) {
        int lj = wave * 80 + t * 16 + lrow;
        #pragma unroll
        for (int iu = 0; iu < 2; ++iu)
            #pragma unroll
            for (int r = 0; r < 4; ++r) {
                int rloc = iu * 16 + lquad * 4 + r;
                int d = lj - rloc;
                int dc = d < 0 ? 0 : (d > 256 ? 256 : d);
                bool ok = (unsigned)d <= 256u;
                float val = ok ? acc[iu][t][r] + b2f(SQ[rloc * LDSW + dc]) : -1e30f;
                acc[iu][t][r] = val;
                m4[iu][r] = fmaxf(m4[iu][r], val);
            }
    }
    #pragma unroll
    for (int iu = 0; iu < 2; ++iu)
        #pragma unroll
        for (int r = 0; r < 4; ++r) {
            #pragma unroll
            for (int off = 1; off < 16; off <<= 1)
                m4[iu][r] = fmaxf(m4[iu][r], __shfl_xor(m4[iu][r], off));
            if (lrow == 0) red[0][wave][iu * 16 + lquad * 4 + r] = m4[iu][r];
        }
    __syncthreads();   // also separates all QR reads from P writes below

    float gmax[2][4];
    #pragma unroll
    for (int iu = 0; iu < 2; ++iu)
        #pragma unroll
        for (int r = 0; r < 4; ++r) {
            int row = iu * 16 + lquad * 4 + r;
            gmax[iu][r] = fmaxf(fmaxf(red[0][0][row], red[0][1][row]),
                                fmaxf(red[0][2][row], red[0][3][row]));
        }

    // exp + store P into (aliased) SQ
    float s4[2][4] = {};
    #pragma unroll
    for (int t = 0; t < 5; ++t) {
        int lj = wave * 80 + t * 16 + lrow;
        #pragma unroll
        for (int iu = 0; iu < 2; ++iu)
            #pragma unroll
            for (int r = 0; r < 4; ++r) {
                float p = __expf(acc[iu][t][r] - gmax[iu][r]);
                s4[iu][r] += p;
                SQ[(iu * 16 + lquad * 4 + r) * LDSW + lj] = f2b(p);
            }
    }
    #pragma unroll
    for (int iu = 0; iu < 2; ++iu)
        #pragma unroll
        for (int r = 0; r < 4; ++r) {
            #pragma unroll
            for (int off = 1; off < 16; off <<= 1)
                s4[iu][r] += __shfl_xor(s4[iu][r], off);
            if (lrow == 0) red[1][wave][iu * 16 + lquad * 4 + r] = s4[iu][r];
        }
    __syncthreads();

    // PV over the 320-key window (wave owns d-slice wave*16+lrow)
    const u16* vbase = VT + ((long)bh * 64 + wave * 16 + lrow) * 512 + w0;
    f32x4 oacc[2] = {};
    bf16x8 vp[10];
    #pragma unroll
    for (int t = 0; t < 10; ++t)
        vp[t] = *(const bf16x8*)(vbase + t * 32 + lquad * 8);
    #pragma unroll
    for (int t = 0; t < 10; ++t)
        #pragma unroll
        for (int iu = 0; iu < 2; ++iu) {
            bf16x8 ap = *(const bf16x8*)(SQ + (iu * 16 + lrow) * LDSW + t * 32 + lquad * 8);
            oacc[iu] = __builtin_amdgcn_mfma_f32_16x16x32_bf16(ap, vp[t], oacc[iu], 0, 0, 0);
        }
    #pragma unroll
    for (int iu = 0; iu < 2; ++iu)
        #pragma unroll
        for (int r = 0; r < 4; ++r) {
            int row = iu * 16 + lquad * 4 + r;
            float inv = 1.0f / (red[1][0][row] + red[1][1][row] + red[1][2][row] + red[1][3][row]);
            attnOut[(long)(b * 256 + i0 + row) * 1024 + h * 64 + wave * 16 + lrow] = f2b(oacc[iu][r] * inv);
        }
}

// ---------------- launch ----------------

extern "C" void kernel_launch(void* const* d_in, const int* in_sizes, int n_in,
                              void* d_out, int out_size, void* d_ws, size_t ws_size,
                              hipStream_t stream) {
    (void)in_sizes; (void)n_in; (void)out_size; (void)ws_size;
    const float* x    = (const float*)d_in[0];
    const float* h    = (const float*)d_in[1];
    const float* Wqkv = (const float*)d_in[2];
    const float* Wkr  = (const float*)d_in[3];
    const float* R    = (const float*)d_in[4];
    const float* u    = (const float*)d_in[5];
    const float* v    = (const float*)d_in[6];
    const float* Wout = (const float*)d_in[7];
    float* out = (float*)d_out;

    char* ws = (char*)d_ws;
    size_t off = 0;
    auto alloc = [&](size_t bytes) -> void* {
        void* p = ws + off;
        off = (off + bytes + 255) & ~(size_t)255;
        return p;
    };
    u16* catBF  = (u16*)alloc(4096L * 1024 * 2);   // [b*512][1024]
    u16* WqkvT  = (u16*)alloc(3072L * 1024 * 2);
    u16* WkrT   = (u16*)alloc(1024L * 1024 * 2);
    u16* WoutT  = (u16*)alloc(1024L * 1024 * 2);
    u16* RWg    = (u16*)alloc(320L * 1024 * 2);    // live shift rows of R@Wkr
    u16* Q      = (u16*)alloc(16L * 8 * 256 * 64 * 2);   // [h][b][i][d], 0.125*q
    u16* Kt     = (u16*)alloc(8L * 16 * 512 * 64 * 2);   // [b][h][t][d]
    u16* VT     = (u16*)alloc(8L * 16 * 64 * 512 * 2 + 1024);  // [b][h][d][t] + 1KB guard
    u16* attnO  = (u16*)alloc(2048L * 1024 * 2);   // [b*256+i][h*64+d]
    u16* vtGuard = VT + 8L * 16 * 64 * 512;

    prep_kernel<<<7169, 256, 0, stream>>>(x, h, catBF, Wqkv, WqkvT, Wkr, WkrT, Wout, WoutT, vtGuard);
    qkv_rwg_kernel<<<1360, 256, 0, stream>>>(WqkvT, catBF, EpiQKV4{Q, Kt, VT}, R, WkrT, RWg);
    attn_kernel<<<1024, 256, 0, stream>>>(Q, Kt, VT, RWg, u, v, attnO);
    outproj_kernel<<<512, 256, 0, stream>>>(attnO, WoutT, out);
}

// Round 7
// 159.836 us; speedup vs baseline: 1.0558x; 1.0558x over previous
//
#include <hip/hip_runtime.h>
#include <hip/hip_bf16.h>
#include <math.h>

typedef unsigned short u16;
typedef short bf16x8 __attribute__((ext_vector_type(8)));
typedef float f32x4 __attribute__((ext_vector_type(4)));

__device__ __forceinline__ u16 f2b(float f) {
    __hip_bfloat16 h = __float2bfloat16(f);
    return *reinterpret_cast<u16*>(&h);
}
__device__ __forceinline__ float b2f(u16 v) {
    __hip_bfloat16 h;
    *reinterpret_cast<u16*>(&h) = v;
    return __bfloat162float(h);
}

__device__ __forceinline__ void gload_lds16(const void* g, void* l) {
    __builtin_amdgcn_global_load_lds(
        (const __attribute__((address_space(1))) void*)g,
        (__attribute__((address_space(3))) void*)l, 16, 0, 0);
}

// ---------------- epilogues ----------------

// Tile epilogue for transposed QKV GEMM: rowp = weight-col base (4 consecutive
// values in vals), colp = pos index. Q/K stores ushort4 coalesced; V stores
// transposed (VT[bh][d][t]) directly.
struct EpiQKV4 {
    u16 *Q, *Kt, *Vt;
    __device__ void operator()(int rowp, int colp, f32x4 vals) const {
        int b = colp >> 9, pos = colp & 511;
        int sec = rowp >> 10, cc = rowp & 1023;
        int head = cc >> 6, d0 = cc & 63;
        if (sec == 0) {
            if (pos < 256) return;
            ushort4 o;
            o.x = f2b(vals[0] * 0.125f); o.y = f2b(vals[1] * 0.125f);
            o.z = f2b(vals[2] * 0.125f); o.w = f2b(vals[3] * 0.125f);
            *(ushort4*)(Q + (long)((head * 8 + b) * 256 + (pos - 256)) * 64 + d0) = o;
        } else if (sec == 1) {
            ushort4 o;
            o.x = f2b(vals[0]); o.y = f2b(vals[1]);
            o.z = f2b(vals[2]); o.w = f2b(vals[3]);
            *(ushort4*)(Kt + (long)((b * 16 + head) * 512 + pos) * 64 + d0) = o;
        } else {
            // transposed store: VT[(b*16+head)*64 + d][pos]
            #pragma unroll
            for (int r = 0; r < 4; ++r)
                Vt[(long)((b * 16 + head) * 64 + d0 + r) * 512 + pos] = f2b(vals[r]);
        }
    }
};

struct EpiStoreBf {
    u16* C; long ldc; long strideZ;
    __device__ void operator()(int z, int row, int col, float val) const {
        C[(long)z * strideZ + (long)row * ldc + col] = f2b(val);
    }
};

// ---------------- 64x64-tile GEMM body (C = A @ B^T), LDS-staged ----------------
// Requires 14336 bytes of smem (2 x 64 x 56 x 2B).
// AF32: A is f32, converted during staging. ROWMAP: A row remap.

template <typename Epi, bool AF32, bool ROWMAP>
__device__ __forceinline__ void gemm_bt_body(char* smem, int bx, int by, int bz,
                                             const void* __restrict__ Av, int lda, long strideAz,
                                             const u16* __restrict__ B, int ldb, long strideBz,
                                             int K, Epi epi) {
    constexpr int LDT = 56;
    u16* As = (u16*)smem;
    u16* Bs = As + 64 * LDT;
    int n0 = bx * 64, m0 = by * 64, z = bz;
    const u16* Bb = B + (long)z * strideBz + (long)n0 * ldb;
    int tid = threadIdx.x;
    int wave = tid >> 6, lane = tid & 63;
    int wm = wave >> 1, wn = wave & 1;
    int lrow = lane & 15, lquad = lane >> 4;
    int srow = tid >> 2, scol = (tid & 3) * 8;
    f32x4 acc[2][2] = {};
    for (int k0 = 0; k0 < K; k0 += 32) {
        if constexpr (AF32) {
            long arow = m0 + srow;
            if constexpr (ROWMAP) arow = (arow < 256) ? 768 + arow : 0;
            const float* src = (const float*)Av + (long)z * strideAz + arow * lda + k0 + scol;
            float4 f0 = *(const float4*)src;
            float4 f1 = *(const float4*)(src + 4);
            bf16x8 vv;
            vv[0] = (short)f2b(f0.x); vv[1] = (short)f2b(f0.y);
            vv[2] = (short)f2b(f0.z); vv[3] = (short)f2b(f0.w);
            vv[4] = (short)f2b(f1.x); vv[5] = (short)f2b(f1.y);
            vv[6] = (short)f2b(f1.z); vv[7] = (short)f2b(f1.w);
            *(bf16x8*)(As + srow * LDT + scol) = vv;
        } else {
            const u16* Ab = (const u16*)Av + (long)z * strideAz + (long)m0 * lda;
            *(bf16x8*)(As + srow * LDT + scol) = *(const bf16x8*)(Ab + (long)srow * lda + k0 + scol);
        }
        *(bf16x8*)(Bs + srow * LDT + scol) = *(const bf16x8*)(Bb + (long)srow * ldb + k0 + scol);
        __syncthreads();
        bf16x8 af[2], bfr[2];
        #pragma unroll
        for (int mt = 0; mt < 2; ++mt)
            af[mt] = *(const bf16x8*)(As + (wm * 32 + mt * 16 + lrow) * LDT + lquad * 8);
        #pragma unroll
        for (int nt = 0; nt < 2; ++nt)
            bfr[nt] = *(const bf16x8*)(Bs + (wn * 32 + nt * 16 + lrow) * LDT + lquad * 8);
        #pragma unroll
        for (int mt = 0; mt < 2; ++mt)
            #pragma unroll
            for (int nt = 0; nt < 2; ++nt)
                acc[mt][nt] = __builtin_amdgcn_mfma_f32_16x16x32_bf16(af[mt], bfr[nt], acc[mt][nt], 0, 0, 0);
        __syncthreads();
    }
    #pragma unroll
    for (int mt = 0; mt < 2; ++mt)
        #pragma unroll
        for (int nt = 0; nt < 2; ++nt)
            #pragma unroll
            for (int r = 0; r < 4; ++r) {
                int row = m0 + wm * 32 + mt * 16 + lquad * 4 + r;
                int col = n0 + wn * 32 + nt * 16 + lrow;
                epi(z, row, col, acc[mt][nt][r]);
            }
}

// ---------------- prep: cast_cat + all three weight transposes + VT guard ----------------
__global__ __launch_bounds__(256) void prep_kernel(const float* __restrict__ x,
                                                   const float* __restrict__ h,
                                                   u16* __restrict__ catBF,
                                                   const float* __restrict__ Wqkv, u16* __restrict__ WqkvT,
                                                   const float* __restrict__ Wkr,  u16* __restrict__ WkrT,
                                                   const float* __restrict__ Wout, u16* __restrict__ WoutT,
                                                   u16* __restrict__ vtGuard) {
    __shared__ float tile[32][33];
    int bid = blockIdx.x, tid = threadIdx.x;
    if (bid == 7168) {
        ((unsigned int*)vtGuard)[tid] = 0u;
        return;
    }
    if (bid < 2048) {
        int idx = (bid * 256 + tid) * 8;
        int c = idx & 1023, r = idx >> 10;
        int b = r >> 9, pos = r & 511;
        const float* src = (pos < 256) ? h + ((long)(b * 256 + pos) * 1024 + c)
                                       : x + ((long)(b * 256 + pos - 256) * 1024 + c);
        float4 f0 = *(const float4*)src;
        float4 f1 = *(const float4*)(src + 4);
        bf16x8 vv;
        vv[0] = (short)f2b(f0.x); vv[1] = (short)f2b(f0.y);
        vv[2] = (short)f2b(f0.z); vv[3] = (short)f2b(f0.w);
        vv[4] = (short)f2b(f1.x); vv[5] = (short)f2b(f1.y);
        vv[6] = (short)f2b(f1.z); vv[7] = (short)f2b(f1.w);
        *(bf16x8*)(catBF + idx) = vv;
        return;
    }
    const float* W; u16* WT; int nb, kb;
    if (bid < 5120) {
        int w = bid - 2048;  // 96 x 32 tiles
        W = Wqkv; WT = WqkvT;
        nb = (w % 96) * 32; kb = (w / 96) * 32;
        int tx = tid & 31, ty = tid >> 5;
        #pragma unroll
        for (int i = 0; i < 32; i += 8)
            tile[ty + i][tx] = W[(long)(kb + ty + i) * 3072 + nb + tx];
    } else {
        int w = bid - 5120;
        if (w < 1024) { W = Wkr; WT = WkrT; }
        else          { W = Wout; WT = WoutT; w -= 1024; }
        nb = (w & 31) * 32; kb = (w >> 5) * 32;
        int tx = tid & 31, ty = tid >> 5;
        #pragma unroll
        for (int i = 0; i < 32; i += 8)
            tile[ty + i][tx] = W[(long)(kb + ty + i) * 1024 + nb + tx];
    }
    __syncthreads();
    int row = tid >> 3;
    int c4 = (tid & 7) * 4;
    ushort4 o;
    o.x = f2b(tile[c4 + 0][row]);
    o.y = f2b(tile[c4 + 1][row]);
    o.z = f2b(tile[c4 + 2][row]);
    o.w = f2b(tile[c4 + 3][row]);
    *(ushort4*)(WT + (long)(nb + row) * 1024 + kb + c4) = o;
}

// ---------------- QKV GEMM (128x128 tiles, BK=32 dbuf, counted vmcnt, slot-swizzle) + RWg ----
// Structure = the verified round-3 44us kernel (2 panels [64][32] per operand
// per buffer, 4 gload_lds per tile, vmcnt(4), 16 MFMAs per compute, 32 KiB
// LDS, 4 blocks/CU), rebuilt verbatim — round-5 died by mixing BK=64 staging
// into the BK=32 loop (double-counted K + buffer overrun).
// Added on top: LDS slot swizzle. Panels are [rows][64 B]; unswizzled, each
// consecutive-8-lane phase of ds_read_b128 hits 2 bank-groups 4-way. Permute
// the GLOBAL source 16B-chunk c = (s - (r>>1))&3 at staging (LDS stays
// linear, rule #21), read slot (lquad + (lrow>>1))&3 -> each phase covers all
// 32 banks once.
__global__ __launch_bounds__(256, 4) void qkv_rwg_kernel(const u16* __restrict__ A, const u16* __restrict__ B,
                                                         EpiQKV4 eq,
                                                         const float* __restrict__ R, const u16* __restrict__ WkrT,
                                                         u16* __restrict__ RWg) {
    __shared__ alignas(16) char smem[32768];
    int bid0 = blockIdx.x;
    if (bid0 >= 640) {
        int bid2 = bid0 - 640;
        gemm_bt_body<EpiStoreBf, true, true>(smem, bid2 & 15, bid2 >> 4, 0,
            (const void*)R, 1024, 0L, WkrT, 1024, 0L, 1024, EpiStoreBf{RWg, 1024, 0});
        return;
    }
    int xcd = bid0 & 7, s = bid0 >> 3;     // s in [0,80): XCD-local block index
    int G = xcd * 10 + (s >> 3);           // global supertile id [0,80)
    int w = s & 7;                         // n-panel within supertile
    int m0, n0;
    if (G < 64) {                          // K/V: 16 m-panels x 4 n-chunks
        int nchunk = G >> 4, mrow = G & 15;
        m0 = 1024 + mrow * 128;
        n0 = (nchunk * 8 + w) * 128;
    } else {                               // Q (live cols): 8 m-panels x 2 n-chunks
        int G2 = G - 64;
        int nchunk = G2 >> 3, mrow = G2 & 7;
        m0 = mrow * 128;
        int c = nchunk * 8 + w;            // live col index [0,16)
        n0 = (c >> 1) * 512 + 256 + (c & 1) * 128;
    }
    int tid = threadIdx.x, wave = tid >> 6, lane = tid & 63;
    int wm = wave >> 1, wn = wave & 1;
    int lrow = lane & 15, lquad = lane >> 4;
    const u16* Ab = A + (long)m0 * 1024;
    const u16* Bb = B + (long)n0 * 1024;
    f32x4 acc[4][4] = {};

    // stage row r = i*64 + (tid>>2): (r>>1)&3 = (tid>>3)&3 (i-invariant).
    // LDS slot s = tid&3 holds global chunk (s - (r>>1))&3.
    int scperm = (((tid & 3) - ((tid >> 3) & 3)) & 3) * 8;   // u16 offset
    // read row rr = w*64+mt*16+lrow: (rr>>1)&3 = (lrow>>1)&3.
    int rsl = ((lquad + (lrow >> 1)) & 3) * 8;               // u16 offset

    // buffer b: As [128][32] at b*8192 (u16), Bs [128][32] at +4096.
    auto stage = [&](int buf, int k0) {
        u16* Asb = (u16*)smem + buf * 8192;
        u16* Bsb = Asb + 4096;
        int col = k0 + scperm;
        #pragma unroll
        for (int i = 0; i < 2; ++i) {
            int rowb = i * 64 + (tid >> 2);
            gload_lds16(Ab + (long)rowb * 1024 + col, Asb + i * 2048 + tid * 8);
            gload_lds16(Bb + (long)rowb * 1024 + col, Bsb + i * 2048 + tid * 8);
        }
    };
    auto compute = [&](int buf) {
        u16* Asb = (u16*)smem + buf * 8192;
        u16* Bsb = Asb + 4096;
        bf16x8 af[4], bfr[4];
        #pragma unroll
        for (int mt = 0; mt < 4; ++mt)
            af[mt] = *(const bf16x8*)(Asb + (wm * 64 + mt * 16 + lrow) * 32 + rsl);
        #pragma unroll
        for (int nt = 0; nt < 4; ++nt)
            bfr[nt] = *(const bf16x8*)(Bsb + (wn * 64 + nt * 16 + lrow) * 32 + rsl);
        #pragma unroll
        for (int mt = 0; mt < 4; ++mt)
            #pragma unroll
            for (int nt = 0; nt < 4; ++nt)
                acc[mt][nt] = __builtin_amdgcn_mfma_f32_16x16x32_bf16(af[mt], bfr[nt], acc[mt][nt], 0, 0, 0);
    };

    stage(0, 0);
    stage(1, 32);
    for (int t = 0; t < 31; ++t) {
        // wait for tile t's 4 loads; tile t+1's 4 remain in flight
        asm volatile("s_waitcnt vmcnt(4)" ::: "memory");
        __builtin_amdgcn_sched_barrier(0);
        __builtin_amdgcn_s_barrier();
        __builtin_amdgcn_sched_barrier(0);
        compute(t & 1);
        __builtin_amdgcn_sched_barrier(0);
        __builtin_amdgcn_s_barrier();          // all waves done reading buf before restage
        __builtin_amdgcn_sched_barrier(0);
        if (t < 30) stage(t & 1, (t + 2) * 32);
    }
    asm volatile("s_waitcnt vmcnt(0)" ::: "memory");
    __builtin_amdgcn_sched_barrier(0);
    __builtin_amdgcn_s_barrier();
    __builtin_amdgcn_sched_barrier(0);
    compute(1);

    #pragma unroll
    for (int mt = 0; mt < 4; ++mt)
        #pragma unroll
        for (int nt = 0; nt < 4; ++nt) {
            int rowp = m0 + wm * 64 + mt * 16 + lquad * 4;
            int colp = n0 + wn * 64 + nt * 16 + lrow;
            eq(rowp, colp, acc[mt][nt]);
        }
}

// ---------------- out-proj: 64x64 tiles, BK=32 dbuf, counted vmcnt, slot-swizzle ----------------
__global__ __launch_bounds__(256, 4) void outproj_kernel(const u16* __restrict__ A,
                                                         const u16* __restrict__ B,
                                                         float* __restrict__ out) {
    __shared__ alignas(16) char smem[16384];
    int bid = blockIdx.x;
    int n0 = (bid & 15) * 64, m0 = (bid >> 4) * 64;
    int tid = threadIdx.x, wave = tid >> 6, lane = tid & 63;
    int wm = wave >> 1, wn = wave & 1;
    int lrow = lane & 15, lquad = lane >> 4;
    const u16* Ab = A + (long)m0 * 1024;
    const u16* Bb = B + (long)n0 * 1024;
    f32x4 acc[2][2] = {};

    int scperm = (((tid & 3) - ((tid >> 3) & 3)) & 3) * 8;
    int rsl = ((lquad + (lrow >> 1)) & 3) * 8;

    // buffer b: As [64][32] at b*4096 (u16), Bs [64][32] at +2048.
    auto stage = [&](int buf, int k0) {
        u16* Asb = (u16*)smem + buf * 4096;
        u16* Bsb = Asb + 2048;
        int row = tid >> 2, col = k0 + scperm;
        gload_lds16(Ab + (long)row * 1024 + col, Asb + tid * 8);
        gload_lds16(Bb + (long)row * 1024 + col, Bsb + tid * 8);
    };
    auto compute = [&](int buf) {
        u16* Asb = (u16*)smem + buf * 4096;
        u16* Bsb = Asb + 2048;
        bf16x8 af[2], bfr[2];
        #pragma unroll
        for (int mt = 0; mt < 2; ++mt)
            af[mt] = *(const bf16x8*)(Asb + (wm * 32 + mt * 16 + lrow) * 32 + rsl);
        #pragma unroll
        for (int nt = 0; nt < 2; ++nt)
            bfr[nt] = *(const bf16x8*)(Bsb + (wn * 32 + nt * 16 + lrow) * 32 + rsl);
        #pragma unroll
        for (int mt = 0; mt < 2; ++mt)
            #pragma unroll
            for (int nt = 0; nt < 2; ++nt)
                acc[mt][nt] = __builtin_amdgcn_mfma_f32_16x16x32_bf16(af[mt], bfr[nt], acc[mt][nt], 0, 0, 0);
    };

    stage(0, 0);
    stage(1, 32);
    for (int t = 0; t < 31; ++t) {
        asm volatile("s_waitcnt vmcnt(2)" ::: "memory");
        __builtin_amdgcn_sched_barrier(0);
        __builtin_amdgcn_s_barrier();
        __builtin_amdgcn_sched_barrier(0);
        compute(t & 1);
        __builtin_amdgcn_sched_barrier(0);
        __builtin_amdgcn_s_barrier();
        __builtin_amdgcn_sched_barrier(0);
        if (t < 30) stage(t & 1, (t + 2) * 32);
    }
    asm volatile("s_waitcnt vmcnt(0)" ::: "memory");
    __builtin_amdgcn_sched_barrier(0);
    __builtin_amdgcn_s_barrier();
    __builtin_amdgcn_sched_barrier(0);
    compute(1);

    #pragma unroll
    for (int mt = 0; mt < 2; ++mt)
        #pragma unroll
        for (int nt = 0; nt < 2; ++nt)
            #pragma unroll
            for (int r = 0; r < 4; ++r)
                out[(long)(m0 + wm * 32 + mt * 16 + lquad * 4 + r) * 1024
                    + n0 + wn * 32 + nt * 16 + lrow] = acc[mt][nt][r];
}

// ---------------- fused attention: 32 query rows per block, QR GEMM fused in ----------------
// Band structure: entry (i,j) visible iff 0 <= j-i <= 256; QR shift column is
// exactly d = j-i. Rows [i0,i0+32) see keys in [i0, i0+288]; 320-key window.
// 32x320 QR tile computed in-kernel into SQ; QR tile and P alias the same
// SQ buffer. s_setprio(1) wraps the QK^T and PV MFMA clusters.
__global__ __launch_bounds__(256, 4) void attn_kernel(const u16* __restrict__ Qs,
                                                      const u16* __restrict__ Kt,
                                                      const u16* __restrict__ VT,
                                                      const u16* __restrict__ RWg,
                                                      const float* __restrict__ uvec,
                                                      const float* __restrict__ vvec,
                                                      u16* __restrict__ attnOut) {
    constexpr int LDSW = 328;          // 320 + 8 pad; 656B row stride = 2-way banks (free)
    __shared__ alignas(16) u16 SQ[32 * LDSW];   // phase 1: QR tile; phase 2: P
    __shared__ float red[2][4][32];
    int id = blockIdx.x;
    int bh = id & 127, it = id >> 7;
    int b = bh >> 4, h = bh & 15;
    int i0 = it * 32;
    int w0 = i0;                       // key window [w0, w0+320)
    int tid = threadIdx.x, wave = tid >> 6, lane = tid & 63;
    int lrow = lane & 15, lquad = lane >> 4;

    // Q fragments: aq = 0.125q + 0.125u (QK), aqv = 0.125q + 0.125v (QR)
    bf16x8 aq[2][2], aqv[2][2];
    #pragma unroll
    for (int iu = 0; iu < 2; ++iu) {
        const u16* qbase = Qs + (long)((h * 8 + b) * 256 + i0 + iu * 16 + lrow) * 64;
        bf16x8 q0 = *(const bf16x8*)(qbase + lquad * 8);
        bf16x8 q1 = *(const bf16x8*)(qbase + 32 + lquad * 8);
        #pragma unroll
        for (int j = 0; j < 8; ++j) {
            float f0 = b2f((u16)q0[j]), f1 = b2f((u16)q1[j]);
            aq[iu][0][j]  = (short)f2b(f0 + 0.125f * uvec[lquad * 8 + j]);
            aq[iu][1][j]  = (short)f2b(f1 + 0.125f * uvec[32 + lquad * 8 + j]);
            aqv[iu][0][j] = (short)f2b(f0 + 0.125f * vvec[lquad * 8 + j]);
            aqv[iu][1][j] = (short)f2b(f1 + 0.125f * vvec[32 + lquad * 8 + j]);
        }
    }

    // fused QR tile -> SQ[rloc][sc], sc = wave*80 + t*16 + lrow
    const u16* rwbase = RWg + (long)(wave * 80) * 1024 + h * 64;
    #pragma unroll
    for (int t = 0; t < 5; ++t) {
        const u16* rp = rwbase + (long)(t * 16 + lrow) * 1024;
        bf16x8 br0 = *(const bf16x8*)(rp + lquad * 8);
        bf16x8 br1 = *(const bf16x8*)(rp + 32 + lquad * 8);
        int sc = wave * 80 + t * 16 + lrow;
        #pragma unroll
        for (int iu = 0; iu < 2; ++iu) {
            f32x4 qa = {0.f, 0.f, 0.f, 0.f};
            qa = __builtin_amdgcn_mfma_f32_16x16x32_bf16(aqv[iu][0], br0, qa, 0, 0, 0);
            qa = __builtin_amdgcn_mfma_f32_16x16x32_bf16(aqv[iu][1], br1, qa, 0, 0, 0);
            #pragma unroll
            for (int r = 0; r < 4; ++r)
                SQ[(iu * 16 + lquad * 4 + r) * LDSW + sc] = f2b(qa[r]);
        }
    }

    // QK^T over 5 key-tiles per wave (wave owns local keys [wave*80, wave*80+80))
    const u16* kbase = Kt + ((long)bh * 512 + w0 + wave * 80) * 64;
    bf16x8 bk0[5], bk1[5];
    #pragma unroll
    for (int t = 0; t < 5; ++t) {
        const u16* kp = kbase + (long)(t * 16 + lrow) * 64;
        bk0[t] = *(const bf16x8*)(kp + lquad * 8);
        bk1[t] = *(const bf16x8*)(kp + 32 + lquad * 8);
    }
    f32x4 acc[2][5];
    __builtin_amdgcn_s_setprio(1);
    #pragma unroll
    for (int t = 0; t < 5; ++t)
        #pragma unroll
        for (int iu = 0; iu < 2; ++iu) {
            f32x4 a = {0.f, 0.f, 0.f, 0.f};
            a = __builtin_amdgcn_mfma_f32_16x16x32_bf16(aq[iu][0], bk0[t], a, 0, 0, 0);
            a = __builtin_amdgcn_mfma_f32_16x16x32_bf16(aq[iu][1], bk1[t], a, 0, 0, 0);
            acc[iu][t] = a;
        }
    __builtin_amdgcn_s_setprio(0);
    __syncthreads();   // QR tile in LDS complete

    // mask + QR bias + row max.  d = j - i; visible iff 0 <= d <= 256.
    float m4[2][4];
    #pragma unroll
    for (int iu = 0; iu < 2; ++iu)
        #pragma unroll
        for (int r = 0; r < 4; ++r) m4[iu][r] = -1e30f;
    #pragma unroll
    for (int t = 0; t < 5; ++t) {
        int lj = wave * 80 + t * 16 + lrow;
        #pragma unroll
        for (int iu = 0; iu < 2; ++iu)
            #pragma unroll
            for (int r = 0; r < 4; ++r) {
                int rloc = iu * 16 + lquad * 4 + r;
                int d = lj - rloc;
                int dc = d < 0 ? 0 : (d > 256 ? 256 : d);
                bool ok = (unsigned)d <= 256u;
                float val = ok ? acc[iu][t][r] + b2f(SQ[rloc * LDSW + dc]) : -1e30f;
                acc[iu][t][r] = val;
                m4[iu][r] = fmaxf(m4[iu][r], val);
            }
    }
    #pragma unroll
    for (int iu = 0; iu < 2; ++iu)
        #pragma unroll
        for (int r = 0; r < 4; ++r) {
            #pragma unroll
            for (int off = 1; off < 16; off <<= 1)
                m4[iu][r] = fmaxf(m4[iu][r], __shfl_xor(m4[iu][r], off));
            if (lrow == 0) red[0][wave][iu * 16 + lquad * 4 + r] = m4[iu][r];
        }
    __syncthreads();   // also separates all QR reads from P writes below

    float gmax[2][4];
    #pragma unroll
    for (int iu = 0; iu < 2; ++iu)
        #pragma unroll
        for (int r = 0; r < 4; ++r) {
            int row = iu * 16 + lquad * 4 + r;
            gmax[iu][r] = fmaxf(fmaxf(red[0][0][row], red[0][1][row]),
                                fmaxf(red[0][2][row], red[0][3][row]));
        }

    // exp + store P into (aliased) SQ
    float s4[2][4] = {};
    #pragma unroll
    for (int t = 0; t < 5; ++t) {
        int lj = wave * 80 + t * 16 + lrow;
        #pragma unroll
        for (int iu = 0; iu < 2; ++iu)
            #pragma unroll
            for (int r = 0; r < 4; ++r) {
                float p = __expf(acc[iu][t][r] - gmax[iu][r]);
                s4[iu][r] += p;
                SQ[(iu * 16 + lquad * 4 + r) * LDSW + lj] = f2b(p);
            }
    }
    #pragma unroll
    for (int iu = 0; iu < 2; ++iu)
        #pragma unroll
        for (int r = 0; r < 4; ++r) {
            #pragma unroll
            for (int off = 1; off < 16; off <<= 1)
                s4[iu][r] += __shfl_xor(s4[iu][r], off);
            if (lrow == 0) red[1][wave][iu * 16 + lquad * 4 + r] = s4[iu][r];
        }
    __syncthreads();

    // PV over the 320-key window (wave owns d-slice wave*16+lrow)
    const u16* vbase = VT + ((long)bh * 64 + wave * 16 + lrow) * 512 + w0;
    f32x4 oacc[2] = {};
    bf16x8 vp[10];
    #pragma unroll
    for (int t = 0; t < 10; ++t)
        vp[t] = *(const bf16x8*)(vbase + t * 32 + lquad * 8);
    __builtin_amdgcn_s_setprio(1);
    #pragma unroll
    for (int t = 0; t < 10; ++t)
        #pragma unroll
        for (int iu = 0; iu < 2; ++iu) {
            bf16x8 ap = *(const bf16x8*)(SQ + (iu * 16 + lrow) * LDSW + t * 32 + lquad * 8);
            oacc[iu] = __builtin_amdgcn_mfma_f32_16x16x32_bf16(ap, vp[t], oacc[iu], 0, 0, 0);
        }
    __builtin_amdgcn_s_setprio(0);
    #pragma unroll
    for (int iu = 0; iu < 2; ++iu)
        #pragma unroll
        for (int r = 0; r < 4; ++r) {
            int row = iu * 16 + lquad * 4 + r;
            float inv = 1.0f / (red[1][0][row] + red[1][1][row] + red[1][2][row] + red[1][3][row]);
            attnOut[(long)(b * 256 + i0 + row) * 1024 + h * 64 + wave * 16 + lrow] = f2b(oacc[iu][r] * inv);
        }
}

// ---------------- launch ----------------

extern "C" void kernel_launch(void* const* d_in, const int* in_sizes, int n_in,
                              void* d_out, int out_size, void* d_ws, size_t ws_size,
                              hipStream_t stream) {
    (void)in_sizes; (void)n_in; (void)out_size; (void)ws_size;
    const float* x    = (const float*)d_in[0];
    const float* h    = (const float*)d_in[1];
    const float* Wqkv = (const float*)d_in[2];
    const float* Wkr  = (const float*)d_in[3];
    const float* R    = (const float*)d_in[4];
    const float* u    = (const float*)d_in[5];
    const float* v    = (const float*)d_in[6];
    const float* Wout = (const float*)d_in[7];
    float* out = (float*)d_out;

    char* ws = (char*)d_ws;
    size_t off = 0;
    auto alloc = [&](size_t bytes) -> void* {
        void* p = ws + off;
        off = (off + bytes + 255) & ~(size_t)255;
        return p;
    };
    u16* catBF  = (u16*)alloc(4096L * 1024 * 2);   // [b*512][1024]
    u16* WqkvT  = (u16*)alloc(3072L * 1024 * 2);
    u16* WkrT   = (u16*)alloc(1024L * 1024 * 2);
    u16* WoutT  = (u16*)alloc(1024L * 1024 * 2);
    u16* RWg    = (u16*)alloc(320L * 1024 * 2);    // live shift rows of R@Wkr
    u16* Q      = (u16*)alloc(16L * 8 * 256 * 64 * 2);   // [h][b][i][d], 0.125*q
    u16* Kt     = (u16*)alloc(8L * 16 * 512 * 64 * 2);   // [b][h][t][d]
    u16* VT     = (u16*)alloc(8L * 16 * 64 * 512 * 2 + 1024);  // [b][h][d][t] + 1KB guard
    u16* attnO  = (u16*)alloc(2048L * 1024 * 2);   // [b*256+i][h*64+d]
    u16* vtGuard = VT + 8L * 16 * 64 * 512;

    prep_kernel<<<7169, 256, 0, stream>>>(x, h, catBF, Wqkv, WqkvT, Wkr, WkrT, Wout, WoutT, vtGuard);
    qkv_rwg_kernel<<<720, 256, 0, stream>>>(WqkvT, catBF, EpiQKV4{Q, Kt, VT}, R, WkrT, RWg);
    attn_kernel<<<1024, 256, 0, stream>>>(Q, Kt, VT, RWg, u, v, attnO);
    outproj_kernel<<<512, 256, 0, stream>>>(attnO, WoutT, out);
}